// Round 4
// baseline (124.341 us; speedup 1.0000x reference)
//
#include <hip/hip_runtime.h>
#include <math.h>

// B=2, C=1, H=W=2048, RADIUS=1, RK=3; J center plane is zeroed in setup.
namespace {
constexpr int H = 2048;
constexpr int W = 2048;
constexpr int NPIX = H * W;            // 2^22
constexpr int B = 2;
constexpr float DECf = 0.95f;
constexpr float OMDf = 1.0f - 0.95f;
}

using f4 = __attribute__((ext_vector_type(4))) float;

// 4 px/thread (float4 per lane), 256 threads/block, half-row blocks.
// Grid = B*H*2 = 8192, XCD-chunked bijective swizzle (8192 % 8 == 0).
// R4 change: ONE sched_barrier(0) after the load block. R3's VGPR=52 proved
// the allocator sank the J loads into the dot loop (load->wait->FMA per
// plane, ~8 outstanding). The barrier forbids sinking: all ~24 VMEM issue
// back-to-back, waitcnts land after the barrier -> per-wave MLP ~24 loads.
// Numerics: decision path (tap-sum, delta_e, exp, compare) f64 (passed 3x);
// EMA observables f32 (passed R3, absmax 0.0078 vs thr 0.041).
__global__ __launch_bounds__(256, 4) void ising_step_kernel(
    const float* __restrict__ x,      // (B, 2, H, W): s then b
    const float* __restrict__ obvs,   // (B, 4, H, W): e, e2, c, m
    const float* __restrict__ Jm,     // (1, 9, N)
    const float* __restrict__ rs,     // (B, 1, H, W)
    const float* __restrict__ rd,     // (1, 1, H, W)
    float* __restrict__ out)          // state (B,2,N) ++ obvs_out (B,4,N)
{
  const int bid = blockIdx.x;
  const int u   = ((bid & 7) << 10) | (bid >> 3);   // 8 XCDs x 1024 units
  const int bi  = u >> 12;                          // 4096 units per batch
  const int h   = (u >> 1) & (H - 1);
  const int w0  = ((u & 1) << 10) | (threadIdx.x << 2);
  const int n0  = (h << 11) | w0;

  const float* sbase = x + (size_t)bi * 2 * NPIX;
  const int hm = (h - 1) & (H - 1);
  const int hp = (h + 1) & (H - 1);
  const float* rowm = sbase + (size_t)hm * W;
  const float* rowc = sbase + (size_t)h  * W;
  const float* rowp = sbase + (size_t)hp * W;
  const int wl = (w0 - 1) & (W - 1);
  const int wr = (w0 + 4) & (W - 1);

  // ---- load block: ALL global reads issued here ----
  const f4 vm = *(const f4*)(rowm + w0);
  const f4 vc = *(const f4*)(rowc + w0);
  const f4 vp = *(const f4*)(rowp + w0);
  const float lm = rowm[wl], rm = rowm[wr];
  const float lc = rowc[wl], rc = rowc[wr];
  const float lp = rowp[wl], rp = rowp[wr];

  f4 jv[8];
  #pragma unroll
  for (int k = 0; k < 8; ++k) {
    const int kk = (k < 4) ? k : (k + 1);   // skip zeroed center plane
    jv[k] = *(const f4*)(Jm + (size_t)kk * NPIX + n0);
  }

  const f4 bv  = *(const f4*)(sbase + (size_t)NPIX + n0);
  const float* ob = obvs + (size_t)bi * 4 * NPIX + n0;
  const f4 ev  = *(const f4*)(ob);
  const f4 e2v = *(const f4*)(ob + (size_t)NPIX);
  const f4 cv  = *(const f4*)(ob + 2 * (size_t)NPIX);
  const f4 mv  = *(const f4*)(ob + 3 * (size_t)NPIX);
  const f4 rv  = *(const f4*)(rs + (size_t)bi * NPIX + n0);
  const f4 dv  = *(const f4*)(rd + n0);

  // Fence: nothing (loads included) may be scheduled across this point.
  // Forces all VMEM issues above, all consumption below.
  __builtin_amdgcn_sched_barrier(0);

  const float am[6] = {lm, vm.x, vm.y, vm.z, vm.w, rm};
  const float ac[6] = {lc, vc.x, vc.y, vc.z, vc.w, rc};
  const float ap[6] = {lp, vp.x, vp.y, vp.z, vp.w, rp};

  const float bq[4]  = {bv.x, bv.y, bv.z, bv.w};
  const float eq[4]  = {ev.x, ev.y, ev.z, ev.w};
  const float e2q[4] = {e2v.x, e2v.y, e2v.z, e2v.w};
  const float cq[4]  = {cv.x, cv.y, cv.z, cv.w};
  const float mq[4]  = {mv.x, mv.y, mv.z, mv.w};
  const float rsq[4] = {rv.x, rv.y, rv.z, rv.w};
  const float rdq[4] = {dv.x, dv.y, dv.z, dv.w};

  float so[4], eo[4], e2o[4], co[4], mo[4];
  #pragma unroll
  for (int t = 0; t < 4; ++t) {
    // decision-critical path in f64
    const double sum =
        (double)jv[0][t] * am[t]     + (double)jv[1][t] * am[t + 1] +
        (double)jv[2][t] * am[t + 2] + (double)jv[3][t] * ac[t]     +
        (double)jv[4][t] * ac[t + 2] + (double)jv[5][t] * ap[t]     +
        (double)jv[6][t] * ap[t + 1] + (double)jv[7][t] * ap[t + 2];
    const float sf  = ac[t + 1];
    const double s  = (double)sf;
    const double de = 2.0 * s * sum;
    const double p  = (de <= 0.0) ? 1.0 : exp(-de * (double)bq[t]);
    const bool acc  = ((double)rsq[t] < p) && (rdq[t] > 0.5f);
    // observables in f32
    const float E   = (float)(-s * sum);
    const float bf  = bq[t];
    const float en  = DECf * eq[t]  + OMDf * E;
    const float e2n = DECf * e2q[t] + OMDf * E * E;
    const float cn  = DECf * cq[t]  + OMDf * (e2n - en * en) * bf * bf;
    const float mn  = DECf * mq[t]  + OMDf * sf;
    so[t]  = acc ? -sf : sf;
    eo[t]  = en;
    e2o[t] = e2n;
    co[t]  = cn;
    mo[t]  = mn;
  }

  float* st = out + (size_t)bi * 2 * NPIX;
  float* oo = out + (size_t)B * 2 * NPIX + (size_t)bi * 4 * NPIX;
  *(f4*)(st + n0)                     = (f4){so[0], so[1], so[2], so[3]};
  *(f4*)(st + (size_t)NPIX + n0)      = bv;
  *(f4*)(oo + n0)                     = (f4){eo[0], eo[1], eo[2], eo[3]};
  *(f4*)(oo + (size_t)NPIX + n0)      = (f4){e2o[0], e2o[1], e2o[2], e2o[3]};
  *(f4*)(oo + 2 * (size_t)NPIX + n0)  = (f4){co[0], co[1], co[2], co[3]};
  *(f4*)(oo + 3 * (size_t)NPIX + n0)  = (f4){mo[0], mo[1], mo[2], mo[3]};
}

extern "C" void kernel_launch(void* const* d_in, const int* in_sizes, int n_in,
                              void* d_out, int out_size, void* d_ws, size_t ws_size,
                              hipStream_t stream) {
  const float* x    = (const float*)d_in[0];
  const float* obvs = (const float*)d_in[1];
  const float* Jm   = (const float*)d_in[2];
  const float* rs   = (const float*)d_in[3];
  const float* rd   = (const float*)d_in[4];
  float* out = (float*)d_out;

  constexpr int grid = B * H * 2;   // 8192 half-row blocks
  ising_step_kernel<<<grid, 256, 0, stream>>>(x, obvs, Jm, rs, rd, out);
}

// Round 5
// 114.926 us; speedup vs baseline: 1.0819x; 1.0819x over previous
//
#include <hip/hip_runtime.h>
#include <math.h>

// B=2, C=1, H=W=2048, RADIUS=1, RK=3; J center plane is zeroed in setup.
namespace {
constexpr int H = 2048;
constexpr int W = 2048;
constexpr int NPIX = H * W;            // 2^22
constexpr int B = 2;
constexpr float DECf = 0.95f;
constexpr float OMDf = 1.0f - 0.95f;
}

using f4 = __attribute__((ext_vector_type(4))) float;

// R5: one block = one (row, half) for BOTH batches. J (8 planes, 134 MB) and
// rand_drop (17 MB) are batch-independent -> loaded ONCE and used twice
// (previous grid read them once per batch). Per-thread ILP doubles (two
// independent dot+exp chains). 4 px/thread, 256 thr/block.
// Grid = H*2 = 4096 (%8==0), XCD-chunked bijective swizzle: adjacent rows on
// the same per-XCD L2 so the 3-row s stencil hits L2.
// Numerics: decision path (tap-sum, delta_e, exp, compare) in f64 (passed 4x);
// EMA observables in f32 (passed R3/R4, absmax 0.0078 vs thr 0.041).
__global__ __launch_bounds__(256) void ising_step_kernel(
    const float* __restrict__ x,      // (B, 2, H, W): s then b
    const float* __restrict__ obvs,   // (B, 4, H, W): e, e2, c, m
    const float* __restrict__ Jm,     // (1, 9, N)
    const float* __restrict__ rs,     // (B, 1, H, W)
    const float* __restrict__ rd,     // (1, 1, H, W)
    float* __restrict__ out)          // state (B,2,N) ++ obvs_out (B,4,N)
{
  const int bid = blockIdx.x;
  const int u   = ((bid & 7) << 9) | (bid >> 3);   // 8 XCDs x 512 units
  const int h   = u >> 1;                          // row
  const int w0  = ((u & 1) << 10) | (threadIdx.x << 2);
  const int n0  = (h << 11) | w0;

  const int hm = (h - 1) & (H - 1);
  const int hp = (h + 1) & (H - 1);
  const int wl = (w0 - 1) & (W - 1);
  const int wr = (w0 + 4) & (W - 1);

  // ---- shared (batch-independent) loads: J 8 planes + rand_drop ----
  f4 jv[8];
  #pragma unroll
  for (int k = 0; k < 8; ++k) {
    const int kk = (k < 4) ? k : (k + 1);   // skip zeroed center plane
    jv[k] = *(const f4*)(Jm + (size_t)kk * NPIX + n0);
  }
  const f4 dv = *(const f4*)(rd + n0);

  // ---- per-batch loads (all issued before compute) ----
  f4 vm[2], vc[2], vp[2], bv[2], ev[2], e2v[2], cv[2], mv[2], rv[2];
  float lm[2], rmh[2], lc[2], rch[2], lp[2], rph[2];
  #pragma unroll
  for (int bi = 0; bi < 2; ++bi) {
    const float* sb   = x + (size_t)bi * 2 * NPIX;
    const float* rowm = sb + (size_t)hm * W;
    const float* rowc = sb + (size_t)h  * W;
    const float* rowp = sb + (size_t)hp * W;
    vm[bi] = *(const f4*)(rowm + w0);
    vc[bi] = *(const f4*)(rowc + w0);
    vp[bi] = *(const f4*)(rowp + w0);
    lm[bi] = rowm[wl];  rmh[bi] = rowm[wr];
    lc[bi] = rowc[wl];  rch[bi] = rowc[wr];
    lp[bi] = rowp[wl];  rph[bi] = rowp[wr];
    bv[bi] = *(const f4*)(sb + (size_t)NPIX + n0);
    const float* ob = obvs + (size_t)bi * 4 * NPIX + n0;
    ev[bi]  = *(const f4*)(ob);
    e2v[bi] = *(const f4*)(ob + (size_t)NPIX);
    cv[bi]  = *(const f4*)(ob + 2 * (size_t)NPIX);
    mv[bi]  = *(const f4*)(ob + 3 * (size_t)NPIX);
    rv[bi]  = *(const f4*)(rs + (size_t)bi * NPIX + n0);
  }

  // ---- compute + store per batch ----
  #pragma unroll
  for (int bi = 0; bi < 2; ++bi) {
    const float am[6] = {lm[bi], vm[bi].x, vm[bi].y, vm[bi].z, vm[bi].w, rmh[bi]};
    const float ac[6] = {lc[bi], vc[bi].x, vc[bi].y, vc[bi].z, vc[bi].w, rch[bi]};
    const float ap[6] = {lp[bi], vp[bi].x, vp[bi].y, vp[bi].z, vp[bi].w, rph[bi]};
    const float bq[4]  = {bv[bi].x, bv[bi].y, bv[bi].z, bv[bi].w};
    const float eq[4]  = {ev[bi].x, ev[bi].y, ev[bi].z, ev[bi].w};
    const float e2q[4] = {e2v[bi].x, e2v[bi].y, e2v[bi].z, e2v[bi].w};
    const float cq[4]  = {cv[bi].x, cv[bi].y, cv[bi].z, cv[bi].w};
    const float mq[4]  = {mv[bi].x, mv[bi].y, mv[bi].z, mv[bi].w};
    const float rsq[4] = {rv[bi].x, rv[bi].y, rv[bi].z, rv[bi].w};
    const float rdq[4] = {dv.x, dv.y, dv.z, dv.w};

    float so[4], eo[4], e2o[4], co[4], mo[4];
    #pragma unroll
    for (int t = 0; t < 4; ++t) {
      // decision-critical path in f64
      const double sum =
          (double)jv[0][t] * am[t]     + (double)jv[1][t] * am[t + 1] +
          (double)jv[2][t] * am[t + 2] + (double)jv[3][t] * ac[t]     +
          (double)jv[4][t] * ac[t + 2] + (double)jv[5][t] * ap[t]     +
          (double)jv[6][t] * ap[t + 1] + (double)jv[7][t] * ap[t + 2];
      const float sf  = ac[t + 1];
      const double s  = (double)sf;
      const double de = 2.0 * s * sum;
      const double p  = (de <= 0.0) ? 1.0 : exp(-de * (double)bq[t]);
      const bool acc  = ((double)rsq[t] < p) && (rdq[t] > 0.5f);
      // observables in f32
      const float E   = (float)(-s * sum);
      const float bf  = bq[t];
      const float en  = DECf * eq[t]  + OMDf * E;
      const float e2n = DECf * e2q[t] + OMDf * E * E;
      const float cn  = DECf * cq[t]  + OMDf * (e2n - en * en) * bf * bf;
      const float mn  = DECf * mq[t]  + OMDf * sf;
      so[t]  = acc ? -sf : sf;
      eo[t]  = en;
      e2o[t] = e2n;
      co[t]  = cn;
      mo[t]  = mn;
    }

    float* st = out + (size_t)bi * 2 * NPIX;
    float* oo = out + (size_t)B * 2 * NPIX + (size_t)bi * 4 * NPIX;
    *(f4*)(st + n0)                     = (f4){so[0], so[1], so[2], so[3]};
    *(f4*)(st + (size_t)NPIX + n0)      = bv[bi];
    *(f4*)(oo + n0)                     = (f4){eo[0], eo[1], eo[2], eo[3]};
    *(f4*)(oo + (size_t)NPIX + n0)      = (f4){e2o[0], e2o[1], e2o[2], e2o[3]};
    *(f4*)(oo + 2 * (size_t)NPIX + n0)  = (f4){co[0], co[1], co[2], co[3]};
    *(f4*)(oo + 3 * (size_t)NPIX + n0)  = (f4){mo[0], mo[1], mo[2], mo[3]};
  }
}

extern "C" void kernel_launch(void* const* d_in, const int* in_sizes, int n_in,
                              void* d_out, int out_size, void* d_ws, size_t ws_size,
                              hipStream_t stream) {
  const float* x    = (const float*)d_in[0];
  const float* obvs = (const float*)d_in[1];
  const float* Jm   = (const float*)d_in[2];
  const float* rs   = (const float*)d_in[3];
  const float* rd   = (const float*)d_in[4];
  float* out = (float*)d_out;

  constexpr int grid = H * 2;   // 4096 (row, half) blocks, both batches each
  ising_step_kernel<<<grid, 256, 0, stream>>>(x, obvs, Jm, rs, rd, out);
}